// Round 8
// baseline (1026914.941 us; speedup 1.0000x reference)
//
#include <hip/hip_runtime.h>
#include <hip/hip_bf16.h>

typedef float f32x4  __attribute__((ext_vector_type(4)));
typedef int   i32x4  __attribute__((ext_vector_type(4)));
typedef short s16x4  __attribute__((ext_vector_type(4)));
typedef short s16x8  __attribute__((ext_vector_type(8)));
typedef __bf16 bf16x8 __attribute__((ext_vector_type(8)));
typedef unsigned int u32;
typedef unsigned long long u64;

#define DEVI static __device__ __forceinline__

DEVI short f2bf(float f){
  u32 u = __builtin_bit_cast(u32,f);
  u += 0x7fffu + ((u>>16)&1u);       // RNE
  return (short)(u>>16);
}
DEVI float sigm(float x){ return 1.f/(1.f+__expf(-x)); }
DEVI float tanh_(float x){ return 1.f - 2.f/(1.f+__expf(2.f*x)); }

DEVI bf16x8 ldbf8(const short* p){ return __builtin_bit_cast(bf16x8, *(const s16x8*)p); }

// Coherent accesses. SYS=true: sc0 sc1 — bypass L1+L2, serviced at MALL/HBM,
// cross-XCD safe (proven r2-r7). SYS=false: sc0 — bypass L1 only, serviced by
// the XCD's shared L2; valid ONLY between WGs functionally verified co-located.
template<bool SYS>
DEVI f32x4 cldv(const void* p){
  f32x4 r;
  if constexpr (SYS)
    asm volatile("global_load_dwordx4 %0, %1, off sc0 sc1" : "=v"(r) : "v"(p) : "memory");
  else
    asm volatile("global_load_dwordx4 %0, %1, off sc0" : "=v"(r) : "v"(p) : "memory");
  return r;   // caller must s_waitcnt vmcnt before use
}
template<bool SYS>
DEVI void cstv8(void* p, u64 v){
  if constexpr (SYS)
    asm volatile("global_store_dwordx2 %0, %1, off sc0 sc1" :: "v"(p), "v"(v) : "memory");
  else
    asm volatile("global_store_dwordx2 %0, %1, off sc0" :: "v"(p), "v"(v) : "memory");
}
template<bool SYS>
DEVI void cstv4(int* p, int v){
  if constexpr (SYS)
    asm volatile("global_store_dword %0, %1, off sc0 sc1" :: "v"(p), "v"(v) : "memory");
  else
    asm volatile("global_store_dword %0, %1, off sc0" :: "v"(p), "v"(v) : "memory");
}
template<bool SYS>
DEVI int cldv4(const int* p){   // includes its own waitcnt (probe/poll use)
  int r;
  if constexpr (SYS)
    asm volatile("global_load_dword %0, %1, off sc0 sc1\n\ts_waitcnt vmcnt(0)"
                 : "=v"(r) : "v"(p) : "memory");
  else
    asm volatile("global_load_dword %0, %1, off sc0\n\ts_waitcnt vmcnt(0)"
                 : "=v"(r) : "v"(p) : "memory");
  return r;
}

struct TrueT  { static constexpr bool v = true;  };
struct FalseT { static constexpr bool v = false; };

#define NSTEP 255

// ---------------- workspace byte offsets ----------------
#define WS_H1F      0u            // 256*256*4       = 262144
#define WS_H1BF     262144u       // 256*256*2       = 131072
#define WS_ABUF     393216u       // 256*512*2       = 262144
#define WS_CELLW    655360u       // 1024*512*2      = 1048576
#define WS_WIH      1703936u      // 2*2048*512*2    = 4194304
#define WS_WPACK    5898240u      // 4194304
#define WS_GATES1   10092544u     // 256*1024*4      = 1048576
#define WS_GX       11141120u     // 2*2*256*2048*4  = 8388608
#define WS_HBUF     19529728u     // 2*2*256*512*2   = 1048576
#define WS_LDIFF    20578304u     // 255*16*256*4    = 4177920
#define WS_Q        28934144u     // 131072
#define WS_K        29065216u     // 131072
#define WS_SA       29196288u     // 262144
#define WS_HARD     29458432u     // 256*255*4       = 261120
#define WS_FLAGS    29719552u     // 32 groups * 32 slots * 4B = 4096
#define WS_TOK      29723648u     // 32 groups * 8 * 4B = 1024
#define WS_VERD     29724672u     // 32 groups * 8 * 4B = 1024
#define WS_NZ       29725696u     // 4

// ---------------- pack weights to bf16 ----------------
// wpack layout: [d][hb8][w(gate)][ct(4)][kk][lane][8]  for mfma_f32_16x16x32_bf16
//   B-frag: col = lane&15 (within 16-col tile), k = 32*kk + 8*(lane>>4) + j
__global__ void k_pack(const float* __restrict__ lf_whh, const float* __restrict__ lr_whh,
                       const float* __restrict__ cwih, const float* __restrict__ cwhh,
                       const float* __restrict__ lf_wih, const float* __restrict__ lr_wih,
                       short* __restrict__ wpack, short* __restrict__ cellw, short* __restrict__ wih)
{
  int bx = blockIdx.x, tid = threadIdx.x;
  if (bx < 1024) {
    int idx = bx*256 + tid;            // [0, 262144) = d*hb8*w*ct*kk*lane
    int lane = idx & 63;
    int kk   = (idx>>6)&15;
    int ct   = (idx>>10)&3;
    int w    = (idx>>12)&3;            // gate index (i,f,g,o)
    int hb8  = (idx>>14)&7;
    int d    = (idx>>17)&1;
    const float* W = d ? lr_whh : lf_whh;
    int wrow = 512*w + hb8*64 + ct*16 + (lane&15);   // W_hh gate-output row
    short v[8];
    #pragma unroll
    for (int jj=0;jj<8;++jj){
      int k = 32*kk + 8*(lane>>4) + jj;
      v[jj] = f2bf(W[(size_t)wrow*512 + k]);
    }
    s16x8 o;
    #pragma unroll
    for (int jj=0;jj<8;++jj) o[jj] = v[jj];
    *(s16x8*)(wpack + (size_t)idx*8) = o;
  } else if (bx < 3072) {
    int e = (bx-1024)*256 + tid;       // [0, 524288): cellW = [w_ih | w_hh]
    int cg = e>>9, k = e&511;
    float val = (k<256) ? cwih[cg*256 + k] : cwhh[cg*256 + (k-256)];
    cellw[e] = f2bf(val);
  } else {
    int e = (bx-3072)*256 + tid;       // [0, 2097152)
    int d = e>>20, r = e & 1048575;
    const float* W = d ? lr_wih : lf_wih;
    wih[e] = f2bf(W[r]);
  }
}

// ---------------- encoder + build [enc | h_in] bf16 ----------------
__global__ void k1a(const float* __restrict__ x, const float* __restrict__ enc_w,
                    const float* __restrict__ enc_b, const float* __restrict__ h_in,
                    short* __restrict__ abuf)
{
  __shared__ float xs[64];
  int b = blockIdx.x, u = threadIdx.x;
  if (u < 64) xs[u] = x[b*64 + u];
  __syncthreads();
  float acc = enc_b[u];
  #pragma unroll 8
  for (int j=0;j<64;++j) acc += xs[j]*enc_w[u*64+j];
  abuf[b*512 + u]       = f2bf(acc);
  abuf[b*512 + 256 + u] = f2bf(h_in[b*256 + u]);
}

// ---------------- first-cell gates GEMM (256x1024, K=512, native 16x16x32) ----------------
__global__ void k1b(const short* __restrict__ abuf, const short* __restrict__ cellw,
                    float* __restrict__ gates1)
{
  int tid = threadIdx.x, w = tid>>6, l = tid&63;
  int m0 = (blockIdx.x&3)*64 + 32*(w&1);
  int n0 = (blockIdx.x>>2)*64 + 32*(w>>1);
  int arow = l&15, ag = l>>4;
  f32x4 acc[2][2] = {};
  #pragma unroll 4
  for (int kk=0; kk<16; ++kk){
    int ko = 32*kk + 8*ag;
    bf16x8 a0 = ldbf8(abuf + (size_t)(m0 + arow)*512 + ko);
    bf16x8 a1 = ldbf8(abuf + (size_t)(m0 + 16 + arow)*512 + ko);
    bf16x8 b0 = ldbf8(cellw + (size_t)(n0 + arow)*512 + ko);
    bf16x8 b1 = ldbf8(cellw + (size_t)(n0 + 16 + arow)*512 + ko);
    acc[0][0] = __builtin_amdgcn_mfma_f32_16x16x32_bf16(a0,b0,acc[0][0],0,0,0);
    acc[0][1] = __builtin_amdgcn_mfma_f32_16x16x32_bf16(a0,b1,acc[0][1],0,0,0);
    acc[1][0] = __builtin_amdgcn_mfma_f32_16x16x32_bf16(a1,b0,acc[1][0],0,0,0);
    acc[1][1] = __builtin_amdgcn_mfma_f32_16x16x32_bf16(a1,b1,acc[1][1],0,0,0);
  }
  #pragma unroll
  for (int rt=0;rt<2;++rt)
    #pragma unroll
    for (int ct=0;ct<2;++ct)
      #pragma unroll
      for (int reg=0;reg<4;++reg)
        gates1[(size_t)(m0 + 16*rt + 4*ag + reg)*1024 + n0 + 16*ct + arow] = acc[rt][ct][reg];
}

// ---------------- first-cell elementwise ----------------
__global__ void k1c(const float* __restrict__ gates1, const float* __restrict__ bih,
                    const float* __restrict__ bhh, const float* __restrict__ c_in,
                    float* __restrict__ out_h, float* __restrict__ out_c,
                    float* __restrict__ h1f, short* __restrict__ h1bf)
{
  int b = blockIdx.x, u = threadIdx.x;
  const float* g = gates1 + (size_t)b*1024;
  float iv = g[u]     + bih[u]     + bhh[u];
  float fv = g[256+u] + bih[256+u] + bhh[256+u];
  float gv = g[512+u] + bih[512+u] + bhh[512+u];
  float ov = g[768+u] + bih[768+u] + bhh[768+u];
  float c = sigm(fv)*c_in[b*256+u] + sigm(iv)*tanh_(gv);
  float h = sigm(ov)*tanh_(c);
  out_h[b*256+u] = h; out_c[b*256+u] = c;
  h1f[b*256+u] = h;   h1bf[b*256+u] = f2bf(h);
}

// ---------------- q / k projections ----------------
__global__ void k_qk(const float* __restrict__ h1, const float* __restrict__ wq_w,
                     const float* __restrict__ wq_b, const float* __restrict__ wk_w,
                     const float* __restrict__ wk_b, float* __restrict__ q, float* __restrict__ k)
{
  __shared__ float hrow[256];
  int b = blockIdx.x, u = threadIdx.x;
  hrow[u] = h1[b*256+u];
  hrow[u+128] = h1[b*256+u+128];
  __syncthreads();
  const float* W  = blockIdx.y ? wk_w : wq_w;
  const float* bb = blockIdx.y ? wk_b : wq_b;
  float* out = blockIdx.y ? k : q;
  float acc = bb[u];
  #pragma unroll 8
  for (int j=0;j<256;++j) acc += hrow[j]*W[u*256+j];
  out[b*128+u] = acc;
}

// ---------------- full score matrix sa = q k^T / sqrt(128) ----------------
__global__ void k_sa(const float* __restrict__ q, const float* __restrict__ k, float* __restrict__ sa)
{
  __shared__ float qrow[128];
  int b = blockIdx.x, j = threadIdx.x;
  if (j < 128) qrow[j] = q[b*128+j];
  __syncthreads();
  float acc = 0.f;
  #pragma unroll 8
  for (int kk=0;kk<128;++kk) acc += qrow[kk]*k[j*128+kk];
  sa[b*256+j] = acc * 0.08838834764831845f;
}

// ---------------- Gx1/Gx2 input-gate precompute (4 GEMMs 256x2048, K=256) ----------------
__global__ void k_gx(const short* __restrict__ h1bf, const short* __restrict__ wih,
                     const float* __restrict__ lf_bih, const float* __restrict__ lf_bhh,
                     const float* __restrict__ lr_bih, const float* __restrict__ lr_bhh,
                     float* __restrict__ gx)
{
  int z = blockIdx.y, d = z>>1, half = z&1;
  int tid = threadIdx.x, w = tid>>6, l = tid&63;
  int m0 = (blockIdx.x&3)*64 + 32*(w&1);
  int n0 = (blockIdx.x>>2)*64 + 32*(w>>1);
  int arow = l&15, ag = l>>4;
  const short* Bb = wih + (size_t)d*2048*512 + 256*half;
  f32x4 acc[2][2] = {};
  #pragma unroll 4
  for (int kk=0;kk<8;++kk){
    int ko = 32*kk + 8*ag;
    bf16x8 a0 = ldbf8(h1bf + (size_t)(m0 + arow)*256 + ko);
    bf16x8 a1 = ldbf8(h1bf + (size_t)(m0 + 16 + arow)*256 + ko);
    bf16x8 b0 = ldbf8(Bb + (size_t)(n0 + arow)*512 + ko);
    bf16x8 b1 = ldbf8(Bb + (size_t)(n0 + 16 + arow)*512 + ko);
    acc[0][0] = __builtin_amdgcn_mfma_f32_16x16x32_bf16(a0,b0,acc[0][0],0,0,0);
    acc[0][1] = __builtin_amdgcn_mfma_f32_16x16x32_bf16(a0,b1,acc[0][1],0,0,0);
    acc[1][0] = __builtin_amdgcn_mfma_f32_16x16x32_bf16(a1,b0,acc[1][0],0,0,0);
    acc[1][1] = __builtin_amdgcn_mfma_f32_16x16x32_bf16(a1,b1,acc[1][1],0,0,0);
  }
  const float* bi = d ? lr_bih : lf_bih;
  const float* bh = d ? lr_bhh : lf_bhh;
  float* out = gx + (size_t)z*256*2048;
  #pragma unroll
  for (int rt=0;rt<2;++rt)
    #pragma unroll
    for (int ct=0;ct<2;++ct){
      int cg = n0 + 16*ct + arow;
      float bias = (half==0) ? (bi[cg] + bh[cg]) : 0.f;
      #pragma unroll
      for (int reg=0;reg<4;++reg)
        out[(size_t)(m0 + 16*rt + 4*ag + reg)*2048 + cg] = acc[rt][ct][reg] + bias;
    }
}

// ---------------- persistent bidirectional LSTM over 255 steps ----------------
// 256 WGs: grp = bid&31 (d x 16-row slab), hb8 = bid>>5 (8 column-WGs / 64 cols).
// Group members have bid ≡ grp (mod 8) -> same XCD under round-robin dispatch.
// FUNCTIONAL CO-LOCATION PROBE (hang-proof): members post tokens via sc0 (which
// stay dirty in the local L2 and are provably invisible cross-XCD, since MALL
// never probes L2s); bounded-spin poll; verdicts exchanged over the reliable
// sc0sc1 path; unanimous visibility -> L2-scope (sc0) exchange, else the proven
// r6 MALL-scope (sc0 sc1) path. Every fast-path spin is budget-bounded, so any
// false-positive becomes a visible absmax failure, never a hang. Rationale:
// r7 counters showed sc0sc1 traffic is serviced from HBM (FETCH_SIZE == the
// coherent read volume) -> each exchange hop costs an HBM round trip; L2-local
// exchange cuts hop latency ~4x and takes the h read-amplification off HBM.
__global__ __launch_bounds__(256,1) void k_rec(
  const short* __restrict__ wpack, const float* __restrict__ gx,
  short* __restrict__ hbuf, float* __restrict__ ldiff,
  const float* __restrict__ lin_w, int* __restrict__ flags,
  int* __restrict__ toks, int* __restrict__ verds)
{
  __shared__ short h_lds[2][16*512];       // 2 x 16KB, 16B-XOR-swizzled
  __shared__ float glds[2][4][16][68];     // 2 x 17KB, padded rows for banks
  __shared__ int s_fast;
  const int tid = threadIdx.x;
  const int w = tid>>6, l = tid&63;
  const int bid = blockIdx.x;
  const int grp = bid & 31;          // (d, g16) — members spaced 32 apart
  const int hb8 = bid >> 5;
  const int d   = grp >> 4;
  const int g16 = grp & 15;
  const int r0  = g16*16;

  // ---- functional co-location probe (one-time, bounded) ----
  {
    int* tok  = toks  + grp*8;
    int* verd = verds + grp*8;
    if (w == 0){
      if (l == 0) cstv4<false>(tok + hb8, 1);      // sc0: visible iff same XCD
      int tv = 1;
      for (int it=0; it<8000; ++it){
        if (l < 8) tv = cldv4<false>(tok + l);
        if (__all(tv != 0)) break;
      }
      int seen = __all(tv != 0);
      if (l == 0) cstv4<true>(verd + hb8, seen ? 2 : 1);   // reliable path
      int vv = 2;
      for (int it=0; it<(1<<22); ++it){
        if (l < 8) vv = cldv4<true>(verd + l);
        if (__all(vv != 0)) break;
        __builtin_amdgcn_s_sleep(1);
      }
      if (l == 0) s_fast = __all(vv == 2) ? 1 : 0;
    }
  }

  // B (weights) resident in registers: 4 ct x 16 kk x bf16x8 = 256 VGPR
  bf16x8 breg[4][16];
  {
    const short* wp = wpack + (size_t)(((d*8+hb8)*4 + w)*4)*16*64*8 + (size_t)l*8;
    #pragma unroll
    for (int ct=0;ct<4;++ct)
      #pragma unroll
      for (int kk=0;kk<16;++kk)
        breg[ct][kk] = ldbf8(wp + (size_t)(ct*16+kk)*64*8);
  }

  const int r_e = tid>>4;            // elementwise row 0..15
  const int j4  = (tid&15)*4;        // hidden-within-block base (0..60)
  const int rg_e = r0 + r_e;         // global agent row
  float gx1c[16], ldwc[4];
  {
    const float* g1 = gx + ((size_t)(d*2)*256 + rg_e)*2048 + hb8*64 + j4;
    #pragma unroll
    for (int g=0;g<4;++g){
      f32x4 v = *(const f32x4*)(g1 + g*512);
      gx1c[g*4+0]=v.x; gx1c[g*4+1]=v.y; gx1c[g*4+2]=v.z; gx1c[g*4+3]=v.w;
    }
    #pragma unroll
    for (int jj=0;jj<4;++jj){
      int col = d*512 + hb8*64 + j4 + jj;
      ldwc[jj] = lin_w[1024+col] - lin_w[col];  // logit1 - logit0 coefficient
    }
  }
  float c_st[4] = {0.f,0.f,0.f,0.f};
  int* slots  = flags + grp*32;            // 32 producer-wave slots for my group
  int* myslot = slots + hb8*4 + w;
  const float* gx2base = gx + (size_t)(d*2+1)*256*2048 + hb8*64 + j4;

  const int s_row = tid>>4;          // staging row 0..15 (== r_e)
  const int c0    = tid&15;
  const int arow = l&15, ag = l>>4;  // 16x16x32 A mapping

  __syncthreads();
  const bool fastp = (s_fast != 0);

  auto loop = [&](auto fc){
    constexpr bool SYS = decltype(fc)::v;
    const int budget = SYS ? (1<<22) : (1<<16);
    for (int tau=0; tau<NSTEP; ++tau){
      const int t = d ? (254-tau) : tau;
      // ---- prefetch gx2 row for this step (independent of h): hides under poll
      f32x4 x2r[4];
      {
        const float* g2 = gx2base + (size_t)(t + (t>=rg_e ? 1:0))*2048;
        #pragma unroll
        for (int g=0;g<4;++g) x2r[g] = *(const f32x4*)(g2 + g*512);
      }
      // ---- poll: lanes 0..7 each watch 4 contiguous slots via dwordx4
      if (tau){
        f32x4 sv = {};
        for (int it=0;;++it){
          if (l < 8) sv = cldv<SYS>(slots + 4*l);
          asm volatile("s_waitcnt vmcnt(0)" ::: "memory");
          int ok = 1;
          if (l < 8){
            i32x4 si = __builtin_bit_cast(i32x4, sv);
            ok = (si.x>=tau) & (si.y>=tau) & (si.z>=tau) & (si.w>=tau);
          }
          if (__all(ok)) break;
          if (it >= budget) break;              // bounded: fail visibly, not hang
          if (SYS) __builtin_amdgcn_s_sleep(1); // back off the MALL on slow path
        }
      }
      const int p = tau&1;
      // ---- stage h(tau) rows r0..r0+15 into swizzled LDS via coherent 16B loads
      {
        const short* hsrc = hbuf + (size_t)((p*2+d)*256 + r0 + s_row)*512;
        f32x4 q[4];
        #pragma unroll
        for (int i=0;i<4;++i)
          q[i] = cldv<SYS>(hsrc + (size_t)(c0 + 16*i)*8);
        asm volatile("s_waitcnt vmcnt(0)" ::: "memory");
        #pragma unroll
        for (int i=0;i<4;++i){
          int c = c0 + 16*i;
          int wb = (16*c) ^ ((s_row&15)<<4);
          *(f32x4*)((char*)h_lds[p] + s_row*1024 + wb) = q[i];
        }
      }
      __syncthreads();                       // barrier A: stage -> frag reads
      // ---- recurrent GEMM: wave w computes gate w, 16 rows x 64 cols, K=512
      f32x4 acc[4] = {};
      #pragma unroll
      for (int kk=0;kk<16;++kk){
        int swz0 = (64*kk + 16*ag) ^ (arow<<4);
        bf16x8 a = __builtin_bit_cast(bf16x8, *(const s16x8*)((char*)h_lds[p] + arow*1024 + swz0));
        acc[0] = __builtin_amdgcn_mfma_f32_16x16x32_bf16(a,breg[0][kk],acc[0],0,0,0);
        acc[1] = __builtin_amdgcn_mfma_f32_16x16x32_bf16(a,breg[1][kk],acc[1],0,0,0);
        acc[2] = __builtin_amdgcn_mfma_f32_16x16x32_bf16(a,breg[2][kk],acc[2],0,0,0);
        acc[3] = __builtin_amdgcn_mfma_f32_16x16x32_bf16(a,breg[3][kk],acc[3],0,0,0);
      }
      #pragma unroll
      for (int ct=0;ct<4;++ct)
        #pragma unroll
        for (int reg=0;reg<4;++reg)
          glds[p][w][4*ag + reg][16*ct + arow] = acc[ct][reg];
      __syncthreads();                       // barrier B: glds write -> EW reads
      // ---- elementwise LSTM update (thread owns (r_e, hb8*64 + j4..j4+3))
      {
        float gvals[16], hv[4];
        #pragma unroll
        for (int g=0; g<4; ++g){
          f32x4 mm = *(const f32x4*)&glds[p][g][r_e][j4];
          gvals[g*4+0] = mm.x + gx1c[g*4+0] + x2r[g].x;
          gvals[g*4+1] = mm.y + gx1c[g*4+1] + x2r[g].y;
          gvals[g*4+2] = mm.z + gx1c[g*4+2] + x2r[g].z;
          gvals[g*4+3] = mm.w + gx1c[g*4+3] + x2r[g].w;
        }
        #pragma unroll
        for (int jj=0;jj<4;++jj){
          float iv = sigm(gvals[jj]);
          float fv = sigm(gvals[4+jj]);
          float gg = tanh_(gvals[8+jj]);
          float ov = sigm(gvals[12+jj]);
          float cc = fv*c_st[jj] + iv*gg;
          c_st[jj] = cc;
          hv[jj] = ov*tanh_(cc);
        }
        // critical path first: h-store -> drain -> post slot (skip on last step)
        if (tau < NSTEP-1){
          short* hdst = hbuf + (size_t)(((p^1)*2+d)*256 + rg_e)*512 + hb8*64 + j4;
          u32 lo = (u32)(unsigned short)f2bf(hv[0]) | ((u32)(unsigned short)f2bf(hv[1])<<16);
          u32 hi = (u32)(unsigned short)f2bf(hv[2]) | ((u32)(unsigned short)f2bf(hv[3])<<16);
          cstv8<SYS>(hdst, (u64)lo | ((u64)hi << 32));
          asm volatile("s_waitcnt vmcnt(0)" ::: "memory");
          if (l==0)
            cstv4<SYS>(myslot, tau+1);
        }
        // off critical path: partial logit-difference for this hidden slice
        float s = hv[0]*ldwc[0] + hv[1]*ldwc[1] + hv[2]*ldwc[2] + hv[3]*ldwc[3];
        s += __shfl_xor(s,1); s += __shfl_xor(s,2); s += __shfl_xor(s,4); s += __shfl_xor(s,8);
        if ((l&15)==0)
          ldiff[((size_t)t*16 + d*8 + hb8)*256 + rg_e] = s;
      }
    }
  };
  if (fastp) loop(FalseT{}); else loop(TrueT{});
}

// ---------------- hard-gumbel bit + count ----------------
__global__ void k_hard(const float* __restrict__ ldiff, const float* __restrict__ lin_b,
                       const float* __restrict__ gumbel, float* __restrict__ hard,
                       int* __restrict__ nz)
{
  int t = blockIdx.x, b = threadIdx.x;
  float s = lin_b[1] - lin_b[0];
  #pragma unroll 8
  for (int k=0;k<16;++k) s += ldiff[((size_t)t*16 + k)*256 + b];
  const float* gp = gumbel + ((size_t)t*256 + b)*2;
  s += gp[1] - gp[0];
  int bit = (s > 0.f) ? 1 : 0;            // argmax==1 requires strictly greater
  hard[(size_t)b*255 + t] = (float)bit;
  unsigned long long ball = __ballot(bit);
  __shared__ int cnt[4];
  if ((threadIdx.x & 63)==0) cnt[threadIdx.x>>6] = __popcll(ball);
  __syncthreads();
  if (threadIdx.x==0) atomicAdd(nz, cnt[0]+cnt[1]+cnt[2]+cnt[3]);
}

// ---------------- gated attention + heads ----------------
__global__ void k_attn(const float* __restrict__ h1, const float* __restrict__ sa,
                       const float* __restrict__ hard,
                       const float* __restrict__ val_w, const float* __restrict__ val_b,
                       const float* __restrict__ head_w, const float* __restrict__ head_b,
                       const int* __restrict__ nz,
                       float* __restrict__ out_act, float* __restrict__ out_val,
                       float* __restrict__ out_d)
{
  __shared__ float red[256];
  __shared__ float at[256];
  __shared__ float wred[4];
  __shared__ float logit[11];
  int b = blockIdx.x, u = threadIdx.x;
  float hd = 0.f, sc = -3.0e38f;
  if (u < 255){
    hd = hard[(size_t)b*255 + u];
    int jsel = u + (u>=b ? 1:0);
    sc = sa[b*256 + jsel] * hd;      // gated-off entries contribute value 0 (matches ref)
  }
  red[u] = sc; __syncthreads();
  for (int st=128; st; st>>=1){ if (u<st) red[u] = fmaxf(red[u], red[u+st]); __syncthreads(); }
  float mx = red[0]; __syncthreads();
  float e = (u<255) ? __expf(sc - mx) : 0.f;
  red[u] = e; __syncthreads();
  for (int st=128; st; st>>=1){ if (u<st) red[u] += red[u+st]; __syncthreads(); }
  float inv = 1.f/red[0]; __syncthreads();
  at[u] = (u<255) ? e*inv*hd : 0.f;
  __syncthreads();
  // comm[b,u] = sum_t attn[t] * h1[idx(b,t), u]
  float comm = 0.f;
  for (int t2=0; t2<255; ++t2){
    int jsel = t2 + (t2>=b ? 1:0);
    comm += at[t2] * h1[(size_t)jsel*256 + u];
  }
  float hb_ = h1[(size_t)b*256 + u];
  // val
  float pv = hb_*val_w[u] + comm*val_w[256+u];
  red[u] = pv; __syncthreads();
  for (int st=128; st; st>>=1){ if (u<st) red[u] += red[u+st]; __syncthreads(); }
  if (u==0) out_val[b] = red[0] + val_b[0];
  // act logits (A=11) + log_softmax
  for (int a=0; a<11; ++a){
    float s = hb_*head_w[a*512+u] + comm*head_w[a*512+256+u];
    s += __shfl_xor(s,32); s += __shfl_xor(s,16); s += __shfl_xor(s,8);
    s += __shfl_xor(s,4);  s += __shfl_xor(s,2);  s += __shfl_xor(s,1);
    if ((u&63)==0) wred[u>>6] = s;
    __syncthreads();
    if (u==0) logit[a] = wred[0]+wred[1]+wred[2]+wred[3] + head_b[a];
    __syncthreads();
  }
  if (u==0){
    float m = logit[0];
    #pragma unroll
    for (int a=1;a<11;++a) m = fmaxf(m, logit[a]);
    float se = 0.f;
    #pragma unroll
    for (int a=0;a<11;++a) se += __expf(logit[a]-m);
    float ls = __logf(se);
    #pragma unroll
    for (int a=0;a<11;++a) out_act[(size_t)b*11 + a] = logit[a] - m - ls;
  }
  if (b==0 && u==0){
    float n = (float)(*nz);
    out_d[0] = n / 65536.f;   // N*N
    out_d[1] = n / 65280.f;   // N*(N-1)
  }
}

// ---------------- host launcher ----------------
extern "C" void kernel_launch(void* const* d_in, const int* in_sizes, int n_in,
                              void* d_out, int out_size, void* d_ws, size_t ws_size,
                              hipStream_t stream)
{
  const float* x      = (const float*)d_in[0];
  const float* h_in   = (const float*)d_in[1];
  const float* c_in   = (const float*)d_in[2];
  const float* gumbel = (const float*)d_in[3];
  const float* enc_w  = (const float*)d_in[4];
  const float* enc_b  = (const float*)d_in[5];
  const float* cwih   = (const float*)d_in[6];
  const float* cwhh   = (const float*)d_in[7];
  const float* cbih   = (const float*)d_in[8];
  const float* cbhh   = (const float*)d_in[9];
  const float* lf_wih = (const float*)d_in[10];
  const float* lf_whh = (const float*)d_in[11];
  const float* lf_bih = (const float*)d_in[12];
  const float* lf_bhh = (const float*)d_in[13];
  const float* lr_wih = (const float*)d_in[14];
  const float* lr_whh = (const float*)d_in[15];
  const float* lr_bih = (const float*)d_in[16];
  const float* lr_bhh = (const float*)d_in[17];
  const float* lin_w  = (const float*)d_in[18];
  const float* lin_b  = (const float*)d_in[19];
  const float* wq_w   = (const float*)d_in[20];
  const float* wq_b   = (const float*)d_in[21];
  const float* wk_w   = (const float*)d_in[22];
  const float* wk_b   = (const float*)d_in[23];
  const float* val_w  = (const float*)d_in[24];
  const float* val_b  = (const float*)d_in[25];
  const float* head_w = (const float*)d_in[26];
  const float* head_b = (const float*)d_in[27];

  char* ws = (char*)d_ws;
  float* h1f   = (float*)(ws + WS_H1F);
  short* h1bf  = (short*)(ws + WS_H1BF);
  short* abuf  = (short*)(ws + WS_ABUF);
  short* cellw = (short*)(ws + WS_CELLW);
  short* wih   = (short*)(ws + WS_WIH);
  short* wpack = (short*)(ws + WS_WPACK);
  float* gates1= (float*)(ws + WS_GATES1);
  float* gx    = (float*)(ws + WS_GX);
  short* hbuf  = (short*)(ws + WS_HBUF);
  float* ldiff = (float*)(ws + WS_LDIFF);
  float* qb    = (float*)(ws + WS_Q);
  float* kb    = (float*)(ws + WS_K);
  float* sab   = (float*)(ws + WS_SA);
  float* hardb = (float*)(ws + WS_HARD);
  int*   flags = (int*)(ws + WS_FLAGS);
  int*   toks  = (int*)(ws + WS_TOK);
  int*   verds = (int*)(ws + WS_VERD);
  int*   nz    = (int*)(ws + WS_NZ);

  float* out_act = (float*)d_out;          // 2816
  float* out_val = out_act + 2816;         // 256
  float* out_h   = out_val + 256;          // 65536
  float* out_c   = out_h + 65536;          // 65536
  float* out_d   = out_c + 65536;          // 2

  hipMemsetAsync(flags, 0, 6148, stream);       // flags + toks + verds + nz
  hipMemsetAsync(hbuf, 0, 1048576, stream);     // zero initial LSTM state

  k_pack<<<11264, 256, 0, stream>>>(lf_whh, lr_whh, cwih, cwhh, lf_wih, lr_wih, wpack, cellw, wih);
  k1a <<<256, 256, 0, stream>>>(x, enc_w, enc_b, h_in, abuf);
  k1b <<<64, 256, 0, stream>>>(abuf, cellw, gates1);
  k1c <<<256, 256, 0, stream>>>(gates1, cbih, cbhh, c_in, out_h, out_c, h1f, h1bf);
  k_qk<<<dim3(256,2), 128, 0, stream>>>(h1f, wq_w, wq_b, wk_w, wk_b, qb, kb);
  k_sa<<<256, 256, 0, stream>>>(qb, kb, sab);
  k_gx<<<dim3(128,4), 256, 0, stream>>>(h1bf, wih, lf_bih, lf_bhh, lr_bih, lr_bhh, gx);
  k_rec<<<256, 256, 0, stream>>>(wpack, gx, hbuf, ldiff, lin_w, flags, toks, verds);
  k_hard<<<255, 256, 0, stream>>>(ldiff, lin_b, gumbel, hardb, nz);
  k_attn<<<256, 256, 0, stream>>>(h1f, sab, hardb, val_w, val_b, head_w, head_b, nz,
                                  out_act, out_val, out_d);
}

// Round 9
// 956.987 us; speedup vs baseline: 1073.0714x; 1073.0714x over previous
//
#include <hip/hip_runtime.h>
#include <hip/hip_bf16.h>

typedef float f32x4  __attribute__((ext_vector_type(4)));
typedef short s16x4  __attribute__((ext_vector_type(4)));
typedef short s16x8  __attribute__((ext_vector_type(8)));
typedef __bf16 bf16x8 __attribute__((ext_vector_type(8)));
typedef unsigned int u32;
typedef unsigned long long u64;

#define DEVI static __device__ __forceinline__

DEVI short f2bf(float f){
  u32 u = __builtin_bit_cast(u32,f);
  u += 0x7fffu + ((u>>16)&1u);       // RNE
  return (short)(u>>16);
}
DEVI float sigm(float x){ return 1.f/(1.f+__expf(-x)); }
DEVI float tanh_(float x){ return 1.f - 2.f/(1.f+__expf(2.f*x)); }

DEVI bf16x8 ldbf8(const short* p){ return __builtin_bit_cast(bf16x8, *(const s16x8*)p); }

// Coherent MALL-scope accesses (bypass L1+L2, cross-XCD safe). Proven r2-r8.
DEVI f32x4 cld16(const void* p){
  f32x4 r;
  asm volatile("global_load_dwordx4 %0, %1, off sc0 sc1" : "=v"(r) : "v"(p) : "memory");
  return r;   // caller must s_waitcnt vmcnt before use
}
DEVI void cst8(void* p, u64 v){
  asm volatile("global_store_dwordx2 %0, %1, off sc0 sc1" :: "v"(p), "v"(v) : "memory");
}

#define GOLD 0x9E3779B97F4A7C15ull
#define NSTEP 255

// ---------------- workspace byte offsets ----------------
#define WS_H1F      0u            // 256*256*4       = 262144
#define WS_H1BF     262144u       // 256*256*2       = 131072
#define WS_ABUF     393216u       // 256*512*2       = 262144
#define WS_CELLW    655360u       // 1024*512*2      = 1048576
#define WS_WIH      1703936u      // 2*2048*512*2    = 4194304
#define WS_WPACK    5898240u      // 4194304
#define WS_GATES1   10092544u     // 256*1024*4      = 1048576 (reused as shadow in k_rec)
#define WS_GX       11141120u     // 2*2*256*2048*4  = 8388608
#define WS_HBUF     19529728u     // 2*2*256*512*2   = 1048576
#define WS_LDIFF    20578304u     // 255*16*256*4    = 4177920
#define WS_Q        28934144u     // 131072
#define WS_K        29065216u     // 131072
#define WS_SA       29196288u     // 262144
#define WS_HARD     29458432u     // 256*255*4       = 261120
#define WS_NZ       29723648u     // 4

// ---------------- pack weights to bf16 ----------------
// wpack layout: [d][hb8][w(gate)][ct(4)][kk][lane][8]  for mfma_f32_16x16x32_bf16
//   B-frag: col = lane&15 (within 16-col tile), k = 32*kk + 8*(lane>>4) + j
__global__ void k_pack(const float* __restrict__ lf_whh, const float* __restrict__ lr_whh,
                       const float* __restrict__ cwih, const float* __restrict__ cwhh,
                       const float* __restrict__ lf_wih, const float* __restrict__ lr_wih,
                       short* __restrict__ wpack, short* __restrict__ cellw, short* __restrict__ wih)
{
  int bx = blockIdx.x, tid = threadIdx.x;
  if (bx < 1024) {
    int idx = bx*256 + tid;            // [0, 262144) = d*hb8*w*ct*kk*lane
    int lane = idx & 63;
    int kk   = (idx>>6)&15;
    int ct   = (idx>>10)&3;
    int w    = (idx>>12)&3;            // gate index (i,f,g,o)
    int hb8  = (idx>>14)&7;
    int d    = (idx>>17)&1;
    const float* W = d ? lr_whh : lf_whh;
    int wrow = 512*w + hb8*64 + ct*16 + (lane&15);   // W_hh gate-output row
    short v[8];
    #pragma unroll
    for (int jj=0;jj<8;++jj){
      int k = 32*kk + 8*(lane>>4) + jj;
      v[jj] = f2bf(W[(size_t)wrow*512 + k]);
    }
    s16x8 o;
    #pragma unroll
    for (int jj=0;jj<8;++jj) o[jj] = v[jj];
    *(s16x8*)(wpack + (size_t)idx*8) = o;
  } else if (bx < 3072) {
    int e = (bx-1024)*256 + tid;       // [0, 524288): cellW = [w_ih | w_hh]
    int cg = e>>9, k = e&511;
    float val = (k<256) ? cwih[cg*256 + k] : cwhh[cg*256 + (k-256)];
    cellw[e] = f2bf(val);
  } else {
    int e = (bx-3072)*256 + tid;       // [0, 2097152)
    int d = e>>20, r = e & 1048575;
    const float* W = d ? lr_wih : lf_wih;
    wih[e] = f2bf(W[r]);
  }
}

// ---------------- encoder + build [enc | h_in] bf16 ----------------
__global__ void k1a(const float* __restrict__ x, const float* __restrict__ enc_w,
                    const float* __restrict__ enc_b, const float* __restrict__ h_in,
                    short* __restrict__ abuf)
{
  __shared__ float xs[64];
  int b = blockIdx.x, u = threadIdx.x;
  if (u < 64) xs[u] = x[b*64 + u];
  __syncthreads();
  float acc = enc_b[u];
  #pragma unroll 8
  for (int j=0;j<64;++j) acc += xs[j]*enc_w[u*64+j];
  abuf[b*512 + u]       = f2bf(acc);
  abuf[b*512 + 256 + u] = f2bf(h_in[b*256 + u]);
}

// ---------------- first-cell gates GEMM (256x1024, K=512, native 16x16x32) ----------------
__global__ void k1b(const short* __restrict__ abuf, const short* __restrict__ cellw,
                    float* __restrict__ gates1)
{
  int tid = threadIdx.x, w = tid>>6, l = tid&63;
  int m0 = (blockIdx.x&3)*64 + 32*(w&1);
  int n0 = (blockIdx.x>>2)*64 + 32*(w>>1);
  int arow = l&15, ag = l>>4;
  f32x4 acc[2][2] = {};
  #pragma unroll 4
  for (int kk=0; kk<16; ++kk){
    int ko = 32*kk + 8*ag;
    bf16x8 a0 = ldbf8(abuf + (size_t)(m0 + arow)*512 + ko);
    bf16x8 a1 = ldbf8(abuf + (size_t)(m0 + 16 + arow)*512 + ko);
    bf16x8 b0 = ldbf8(cellw + (size_t)(n0 + arow)*512 + ko);
    bf16x8 b1 = ldbf8(cellw + (size_t)(n0 + 16 + arow)*512 + ko);
    acc[0][0] = __builtin_amdgcn_mfma_f32_16x16x32_bf16(a0,b0,acc[0][0],0,0,0);
    acc[0][1] = __builtin_amdgcn_mfma_f32_16x16x32_bf16(a0,b1,acc[0][1],0,0,0);
    acc[1][0] = __builtin_amdgcn_mfma_f32_16x16x32_bf16(a1,b0,acc[1][0],0,0,0);
    acc[1][1] = __builtin_amdgcn_mfma_f32_16x16x32_bf16(a1,b1,acc[1][1],0,0,0);
  }
  #pragma unroll
  for (int rt=0;rt<2;++rt)
    #pragma unroll
    for (int ct=0;ct<2;++ct)
      #pragma unroll
      for (int reg=0;reg<4;++reg)
        gates1[(size_t)(m0 + 16*rt + 4*ag + reg)*1024 + n0 + 16*ct + arow] = acc[rt][ct][reg];
}

// ---------------- first-cell elementwise ----------------
__global__ void k1c(const float* __restrict__ gates1, const float* __restrict__ bih,
                    const float* __restrict__ bhh, const float* __restrict__ c_in,
                    float* __restrict__ out_h, float* __restrict__ out_c,
                    float* __restrict__ h1f, short* __restrict__ h1bf)
{
  int b = blockIdx.x, u = threadIdx.x;
  const float* g = gates1 + (size_t)b*1024;
  float iv = g[u]     + bih[u]     + bhh[u];
  float fv = g[256+u] + bih[256+u] + bhh[256+u];
  float gv = g[512+u] + bih[512+u] + bhh[512+u];
  float ov = g[768+u] + bih[768+u] + bhh[768+u];
  float c = sigm(fv)*c_in[b*256+u] + sigm(iv)*tanh_(gv);
  float h = sigm(ov)*tanh_(c);
  out_h[b*256+u] = h; out_c[b*256+u] = c;
  h1f[b*256+u] = h;   h1bf[b*256+u] = f2bf(h);
}

// ---------------- q / k projections ----------------
__global__ void k_qk(const float* __restrict__ h1, const float* __restrict__ wq_w,
                     const float* __restrict__ wq_b, const float* __restrict__ wk_w,
                     const float* __restrict__ wk_b, float* __restrict__ q, float* __restrict__ k)
{
  __shared__ float hrow[256];
  int b = blockIdx.x, u = threadIdx.x;
  hrow[u] = h1[b*256+u];
  hrow[u+128] = h1[b*256+u+128];
  __syncthreads();
  const float* W  = blockIdx.y ? wk_w : wq_w;
  const float* bb = blockIdx.y ? wk_b : wq_b;
  float* out = blockIdx.y ? k : q;
  float acc = bb[u];
  #pragma unroll 8
  for (int j=0;j<256;++j) acc += hrow[j]*W[u*256+j];
  out[b*128+u] = acc;
}

// ---------------- full score matrix sa = q k^T / sqrt(128) ----------------
__global__ void k_sa(const float* __restrict__ q, const float* __restrict__ k, float* __restrict__ sa)
{
  __shared__ float qrow[128];
  int b = blockIdx.x, j = threadIdx.x;
  if (j < 128) qrow[j] = q[b*128+j];
  __syncthreads();
  float acc = 0.f;
  #pragma unroll 8
  for (int kk=0;kk<128;++kk) acc += qrow[kk]*k[j*128+kk];
  sa[b*256+j] = acc * 0.08838834764831845f;
}

// ---------------- Gx1/Gx2 input-gate precompute (4 GEMMs 256x2048, K=256) ----------------
__global__ void k_gx(const short* __restrict__ h1bf, const short* __restrict__ wih,
                     const float* __restrict__ lf_bih, const float* __restrict__ lf_bhh,
                     const float* __restrict__ lr_bih, const float* __restrict__ lr_bhh,
                     float* __restrict__ gx)
{
  int z = blockIdx.y, d = z>>1, half = z&1;
  int tid = threadIdx.x, w = tid>>6, l = tid&63;
  int m0 = (blockIdx.x&3)*64 + 32*(w&1);
  int n0 = (blockIdx.x>>2)*64 + 32*(w>>1);
  int arow = l&15, ag = l>>4;
  const short* Bb = wih + (size_t)d*2048*512 + 256*half;
  f32x4 acc[2][2] = {};
  #pragma unroll 4
  for (int kk=0;kk<8;++kk){
    int ko = 32*kk + 8*ag;
    bf16x8 a0 = ldbf8(h1bf + (size_t)(m0 + arow)*256 + ko);
    bf16x8 a1 = ldbf8(h1bf + (size_t)(m0 + 16 + arow)*256 + ko);
    bf16x8 b0 = ldbf8(Bb + (size_t)(n0 + arow)*512 + ko);
    bf16x8 b1 = ldbf8(Bb + (size_t)(n0 + 16 + arow)*512 + ko);
    acc[0][0] = __builtin_amdgcn_mfma_f32_16x16x32_bf16(a0,b0,acc[0][0],0,0,0);
    acc[0][1] = __builtin_amdgcn_mfma_f32_16x16x32_bf16(a0,b1,acc[0][1],0,0,0);
    acc[1][0] = __builtin_amdgcn_mfma_f32_16x16x32_bf16(a1,b0,acc[1][0],0,0,0);
    acc[1][1] = __builtin_amdgcn_mfma_f32_16x16x32_bf16(a1,b1,acc[1][1],0,0,0);
  }
  const float* bi = d ? lr_bih : lf_bih;
  const float* bh = d ? lr_bhh : lf_bhh;
  float* out = gx + (size_t)z*256*2048;
  #pragma unroll
  for (int rt=0;rt<2;++rt)
    #pragma unroll
    for (int ct=0;ct<2;++ct){
      int cg = n0 + 16*ct + arow;
      float bias = (half==0) ? (bi[cg] + bh[cg]) : 0.f;
      #pragma unroll
      for (int reg=0;reg<4;++reg)
        out[(size_t)(m0 + 16*rt + 4*ag + reg)*2048 + cg] = acc[rt][ct][reg] + bias;
    }
}

// ---------------- persistent bidirectional LSTM over 255 steps ----------------
// 256 WGs: d(2) x g16(16: 16-row slabs) x hb8(8: 64 hidden cols / 256 gate cols).
// SELF-VALIDATING exchange (replaces r6's flag protocol): producer fires its 8B
// h units AND an 8B salted shadow (shadow = data ^ GOLD*(tau+1)) fire-and-forget
// — no vmcnt drain, no slot post, no poll RT. Consumer speculatively reads
// data+shadow batched and validates PER 8B UNIT (8B stores are atomic, so torn
// lines decompose into independently-valid units; stale pairs fail by GOLD*dtau;
// 0xAA poison fails since pat != 0). Retry re-reads ONLY invalid 16B chunks.
// Sync chain: ~1 MALL RT (vs r6's ~4: drain+slot+poll+read). tau=0 stages
// literal zeros (h0 = 0 known) so shadow needs no initialization. Overwrite
// safety: same induction as r6 (produce tau+2 only after validating tau+1).
// All spins bounded -> any protocol bug is a visible absmax failure, not a hang.
__global__ __launch_bounds__(256,1) void k_rec(
  const short* __restrict__ wpack, const float* __restrict__ gx,
  short* __restrict__ hbuf, char* __restrict__ shadow,
  float* __restrict__ ldiff, const float* __restrict__ lin_w)
{
  __shared__ short h_lds[2][16*512];       // 2 x 16KB, 16B-XOR-swizzled
  __shared__ float glds[2][4][16][68];     // 2 x 17KB, padded rows for banks
  const int tid = threadIdx.x;
  const int w = tid>>6, l = tid&63;
  const int bid = blockIdx.x;
  const int d   = bid>>7;
  const int g16 = (bid>>3)&15;
  const int hb8 = bid&7;
  const int r0  = g16*16;

  // B (weights) resident in registers: 4 ct x 16 kk x bf16x8 = 256 VGPR
  bf16x8 breg[4][16];
  {
    const short* wp = wpack + (size_t)(((d*8+hb8)*4 + w)*4)*16*64*8 + (size_t)l*8;
    #pragma unroll
    for (int ct=0;ct<4;++ct)
      #pragma unroll
      for (int kk=0;kk<16;++kk)
        breg[ct][kk] = ldbf8(wp + (size_t)(ct*16+kk)*64*8);
  }

  const int r_e = tid>>4;            // elementwise row 0..15
  const int j4  = (tid&15)*4;        // hidden-within-block base (0..60)
  const int rg_e = r0 + r_e;         // global agent row
  float gx1c[16], ldwc[4];
  {
    const float* g1 = gx + ((size_t)(d*2)*256 + rg_e)*2048 + hb8*64 + j4;
    #pragma unroll
    for (int g=0;g<4;++g){
      f32x4 v = *(const f32x4*)(g1 + g*512);
      gx1c[g*4+0]=v.x; gx1c[g*4+1]=v.y; gx1c[g*4+2]=v.z; gx1c[g*4+3]=v.w;
    }
    #pragma unroll
    for (int jj=0;jj<4;++jj){
      int col = d*512 + hb8*64 + j4 + jj;
      ldwc[jj] = lin_w[1024+col] - lin_w[col];  // logit1 - logit0 coefficient
    }
  }
  float c_st[4] = {0.f,0.f,0.f,0.f};
  const float* gx2base = gx + (size_t)(d*2+1)*256*2048 + hb8*64 + j4;

  const int s_row = tid>>4;          // staging row 0..15 (== r_e)
  const int c0    = tid&15;
  const int arow = l&15, ag = l>>4;  // 16x16x32 A mapping
  u64 vst = 0;                       // GOLD*tau, incremented at loop top

  for (int tau=0; tau<NSTEP; ++tau){
    const int t = d ? (254-tau) : tau;
    const u64 vread = vst;           // salt expected in staged data (= GOLD*tau)
    vst += GOLD;                     // salt for this step's stores (= GOLD*(tau+1))
    // ---- prefetch gx2 row for this step (independent of h): hides under verify
    f32x4 x2r[4];
    {
      const float* g2 = gx2base + (size_t)(t + (t>=rg_e ? 1:0))*2048;
      #pragma unroll
      for (int g=0;g<4;++g) x2r[g] = *(const f32x4*)(g2 + g*512);
    }
    const int p = tau&1;
    // ---- stage h(tau) rows r0..r0+15 into swizzled LDS
    if (tau == 0){
      // h(0) = 0 exactly; no global read, no shadow init needed
      f32x4 z = {};
      #pragma unroll
      for (int i=0;i<4;++i){
        int c = c0 + 16*i;
        int wb = (16*c) ^ ((s_row&15)<<4);
        *(f32x4*)((char*)h_lds[p] + s_row*1024 + wb) = z;
      }
    } else {
      const char* dsrc = (const char*)(hbuf + (size_t)((p*2+d)*256 + r0 + s_row)*512);
      const char* ssrc = shadow + ((size_t)((p*2+d)*256 + r0 + s_row)*512)*2;
      f32x4 q[4], sh[4];
      u32 vm = 0;
      for (int it=0;;++it){
        #pragma unroll
        for (int i=0;i<4;++i) if (!((vm>>i)&1u)){
          q[i]  = cld16(dsrc + (size_t)(c0+16*i)*16);
          sh[i] = cld16(ssrc + (size_t)(c0+16*i)*16);
        }
        asm volatile("s_waitcnt vmcnt(0)" ::: "memory");
        #pragma unroll
        for (int i=0;i<4;++i) if (!((vm>>i)&1u)){
          ulonglong2 dq = __builtin_bit_cast(ulonglong2, q[i]);
          ulonglong2 sq = __builtin_bit_cast(ulonglong2, sh[i]);
          if (((dq.x ^ sq.x) == vread) && ((dq.y ^ sq.y) == vread)) vm |= (1u<<i);
        }
        if (__all(vm == 15u)) break;
        if (it > (1<<20)) break;     // bounded: bug -> visible absmax fail
      }
      #pragma unroll
      for (int i=0;i<4;++i){
        int c = c0 + 16*i;
        int wb = (16*c) ^ ((s_row&15)<<4);
        *(f32x4*)((char*)h_lds[p] + s_row*1024 + wb) = q[i];
      }
    }
    __syncthreads();                       // barrier A: stage -> frag reads
    // ---- recurrent GEMM: wave w computes gate w, 16 rows x 64 cols, K=512
    f32x4 acc[4] = {};
    #pragma unroll
    for (int kk=0;kk<16;++kk){
      int swz0 = (64*kk + 16*ag) ^ (arow<<4);
      bf16x8 a = __builtin_bit_cast(bf16x8, *(const s16x8*)((char*)h_lds[p] + arow*1024 + swz0));
      acc[0] = __builtin_amdgcn_mfma_f32_16x16x32_bf16(a,breg[0][kk],acc[0],0,0,0);
      acc[1] = __builtin_amdgcn_mfma_f32_16x16x32_bf16(a,breg[1][kk],acc[1],0,0,0);
      acc[2] = __builtin_amdgcn_mfma_f32_16x16x32_bf16(a,breg[2][kk],acc[2],0,0,0);
      acc[3] = __builtin_amdgcn_mfma_f32_16x16x32_bf16(a,breg[3][kk],acc[3],0,0,0);
    }
    #pragma unroll
    for (int ct=0;ct<4;++ct)
      #pragma unroll
      for (int reg=0;reg<4;++reg)
        glds[p][w][4*ag + reg][16*ct + arow] = acc[ct][reg];
    __syncthreads();                       // barrier B: glds write -> EW reads
    // ---- elementwise LSTM update (thread owns (r_e, hb8*64 + j4..j4+3))
    {
      float gvals[16], hv[4];
      #pragma unroll
      for (int g=0; g<4; ++g){
        f32x4 mm = *(const f32x4*)&glds[p][g][r_e][j4];
        gvals[g*4+0] = mm.x + gx1c[g*4+0] + x2r[g].x;
        gvals[g*4+1] = mm.y + gx1c[g*4+1] + x2r[g].y;
        gvals[g*4+2] = mm.z + gx1c[g*4+2] + x2r[g].z;
        gvals[g*4+3] = mm.w + gx1c[g*4+3] + x2r[g].w;
      }
      #pragma unroll
      for (int jj=0;jj<4;++jj){
        float iv = sigm(gvals[jj]);
        float fv = sigm(gvals[4+jj]);
        float gg = tanh_(gvals[8+jj]);
        float ov = sigm(gvals[12+jj]);
        float cc = fv*c_st[jj] + iv*gg;
        c_st[jj] = cc;
        hv[jj] = ov*tanh_(cc);
      }
      // fire-and-forget: data + salted shadow; NO drain, NO slot (skip last step)
      if (tau < NSTEP-1){
        size_t boff = ((size_t)(((p^1)*2+d)*256 + rg_e)*512 + hb8*64 + j4) * 2;
        u32 lo = (u32)(unsigned short)f2bf(hv[0]) | ((u32)(unsigned short)f2bf(hv[1])<<16);
        u32 hi = (u32)(unsigned short)f2bf(hv[2]) | ((u32)(unsigned short)f2bf(hv[3])<<16);
        u64 pk = (u64)lo | ((u64)hi << 32);
        cst8((char*)hbuf + boff, pk);
        cst8(shadow + boff, pk ^ vst);
      }
      // off critical path: partial logit-difference for this hidden slice
      float s = hv[0]*ldwc[0] + hv[1]*ldwc[1] + hv[2]*ldwc[2] + hv[3]*ldwc[3];
      s += __shfl_xor(s,1); s += __shfl_xor(s,2); s += __shfl_xor(s,4); s += __shfl_xor(s,8);
      if ((l&15)==0)
        ldiff[((size_t)t*16 + d*8 + hb8)*256 + rg_e] = s;
    }
  }
}

// ---------------- hard-gumbel bit + count ----------------
__global__ void k_hard(const float* __restrict__ ldiff, const float* __restrict__ lin_b,
                       const float* __restrict__ gumbel, float* __restrict__ hard,
                       int* __restrict__ nz)
{
  int t = blockIdx.x, b = threadIdx.x;
  float s = lin_b[1] - lin_b[0];
  #pragma unroll 8
  for (int k=0;k<16;++k) s += ldiff[((size_t)t*16 + k)*256 + b];
  const float* gp = gumbel + ((size_t)t*256 + b)*2;
  s += gp[1] - gp[0];
  int bit = (s > 0.f) ? 1 : 0;            // argmax==1 requires strictly greater
  hard[(size_t)b*255 + t] = (float)bit;
  unsigned long long ball = __ballot(bit);
  __shared__ int cnt[4];
  if ((threadIdx.x & 63)==0) cnt[threadIdx.x>>6] = __popcll(ball);
  __syncthreads();
  if (threadIdx.x==0) atomicAdd(nz, cnt[0]+cnt[1]+cnt[2]+cnt[3]);
}

// ---------------- gated attention + heads ----------------
__global__ void k_attn(const float* __restrict__ h1, const float* __restrict__ sa,
                       const float* __restrict__ hard,
                       const float* __restrict__ val_w, const float* __restrict__ val_b,
                       const float* __restrict__ head_w, const float* __restrict__ head_b,
                       const int* __restrict__ nz,
                       float* __restrict__ out_act, float* __restrict__ out_val,
                       float* __restrict__ out_d)
{
  __shared__ float red[256];
  __shared__ float at[256];
  __shared__ float wred[4];
  __shared__ float logit[11];
  int b = blockIdx.x, u = threadIdx.x;
  float hd = 0.f, sc = -3.0e38f;
  if (u < 255){
    hd = hard[(size_t)b*255 + u];
    int jsel = u + (u>=b ? 1:0);
    sc = sa[b*256 + jsel] * hd;      // gated-off entries contribute value 0 (matches ref)
  }
  red[u] = sc; __syncthreads();
  for (int st=128; st; st>>=1){ if (u<st) red[u] = fmaxf(red[u], red[u+st]); __syncthreads(); }
  float mx = red[0]; __syncthreads();
  float e = (u<255) ? __expf(sc - mx) : 0.f;
  red[u] = e; __syncthreads();
  for (int st=128; st; st>>=1){ if (u<st) red[u] += red[u+st]; __syncthreads(); }
  float inv = 1.f/red[0]; __syncthreads();
  at[u] = (u<255) ? e*inv*hd : 0.f;
  __syncthreads();
  // comm[b,u] = sum_t attn[t] * h1[idx(b,t), u]
  float comm = 0.f;
  for (int t2=0; t2<255; ++t2){
    int jsel = t2 + (t2>=b ? 1:0);
    comm += at[t2] * h1[(size_t)jsel*256 + u];
  }
  float hb_ = h1[(size_t)b*256 + u];
  // val
  float pv = hb_*val_w[u] + comm*val_w[256+u];
  red[u] = pv; __syncthreads();
  for (int st=128; st; st>>=1){ if (u<st) red[u] += red[u+st]; __syncthreads(); }
  if (u==0) out_val[b] = red[0] + val_b[0];
  // act logits (A=11) + log_softmax
  for (int a=0; a<11; ++a){
    float s = hb_*head_w[a*512+u] + comm*head_w[a*512+256+u];
    s += __shfl_xor(s,32); s += __shfl_xor(s,16); s += __shfl_xor(s,8);
    s += __shfl_xor(s,4);  s += __shfl_xor(s,2);  s += __shfl_xor(s,1);
    if ((u&63)==0) wred[u>>6] = s;
    __syncthreads();
    if (u==0) logit[a] = wred[0]+wred[1]+wred[2]+wred[3] + head_b[a];
    __syncthreads();
  }
  if (u==0){
    float m = logit[0];
    #pragma unroll
    for (int a=1;a<11;++a) m = fmaxf(m, logit[a]);
    float se = 0.f;
    #pragma unroll
    for (int a=0;a<11;++a) se += __expf(logit[a]-m);
    float ls = __logf(se);
    #pragma unroll
    for (int a=0;a<11;++a) out_act[(size_t)b*11 + a] = logit[a] - m - ls;
  }
  if (b==0 && u==0){
    float n = (float)(*nz);
    out_d[0] = n / 65536.f;   // N*N
    out_d[1] = n / 65280.f;   // N*(N-1)
  }
}

// ---------------- host launcher ----------------
extern "C" void kernel_launch(void* const* d_in, const int* in_sizes, int n_in,
                              void* d_out, int out_size, void* d_ws, size_t ws_size,
                              hipStream_t stream)
{
  const float* x      = (const float*)d_in[0];
  const float* h_in   = (const float*)d_in[1];
  const float* c_in   = (const float*)d_in[2];
  const float* gumbel = (const float*)d_in[3];
  const float* enc_w  = (const float*)d_in[4];
  const float* enc_b  = (const float*)d_in[5];
  const float* cwih   = (const float*)d_in[6];
  const float* cwhh   = (const float*)d_in[7];
  const float* cbih   = (const float*)d_in[8];
  const float* cbhh   = (const float*)d_in[9];
  const float* lf_wih = (const float*)d_in[10];
  const float* lf_whh = (const float*)d_in[11];
  const float* lf_bih = (const float*)d_in[12];
  const float* lf_bhh = (const float*)d_in[13];
  const float* lr_wih = (const float*)d_in[14];
  const float* lr_whh = (const float*)d_in[15];
  const float* lr_bih = (const float*)d_in[16];
  const float* lr_bhh = (const float*)d_in[17];
  const float* lin_w  = (const float*)d_in[18];
  const float* lin_b  = (const float*)d_in[19];
  const float* wq_w   = (const float*)d_in[20];
  const float* wq_b   = (const float*)d_in[21];
  const float* wk_w   = (const float*)d_in[22];
  const float* wk_b   = (const float*)d_in[23];
  const float* val_w  = (const float*)d_in[24];
  const float* val_b  = (const float*)d_in[25];
  const float* head_w = (const float*)d_in[26];
  const float* head_b = (const float*)d_in[27];

  char* ws = (char*)d_ws;
  float* h1f   = (float*)(ws + WS_H1F);
  short* h1bf  = (short*)(ws + WS_H1BF);
  short* abuf  = (short*)(ws + WS_ABUF);
  short* cellw = (short*)(ws + WS_CELLW);
  short* wih   = (short*)(ws + WS_WIH);
  short* wpack = (short*)(ws + WS_WPACK);
  float* gates1= (float*)(ws + WS_GATES1);   // reused as k_rec shadow (1MB, dead after k1c)
  float* gx    = (float*)(ws + WS_GX);
  short* hbuf  = (short*)(ws + WS_HBUF);
  float* ldiff = (float*)(ws + WS_LDIFF);
  float* qb    = (float*)(ws + WS_Q);
  float* kb    = (float*)(ws + WS_K);
  float* sab   = (float*)(ws + WS_SA);
  float* hardb = (float*)(ws + WS_HARD);
  int*   nz    = (int*)(ws + WS_NZ);

  float* out_act = (float*)d_out;          // 2816
  float* out_val = out_act + 2816;         // 256
  float* out_h   = out_val + 256;          // 65536
  float* out_c   = out_h + 65536;          // 65536
  float* out_d   = out_c + 65536;          // 2

  hipMemsetAsync(nz, 0, 4, stream);

  k_pack<<<11264, 256, 0, stream>>>(lf_whh, lr_whh, cwih, cwhh, lf_wih, lr_wih, wpack, cellw, wih);
  k1a <<<256, 256, 0, stream>>>(x, enc_w, enc_b, h_in, abuf);
  k1b <<<64, 256, 0, stream>>>(abuf, cellw, gates1);
  k1c <<<256, 256, 0, stream>>>(gates1, cbih, cbhh, c_in, out_h, out_c, h1f, h1bf);
  k_qk<<<dim3(256,2), 128, 0, stream>>>(h1f, wq_w, wq_b, wk_w, wk_b, qb, kb);
  k_sa<<<256, 256, 0, stream>>>(qb, kb, sab);
  k_gx<<<dim3(128,4), 256, 0, stream>>>(h1bf, wih, lf_bih, lf_bhh, lr_bih, lr_bhh, gx);
  k_rec<<<256, 256, 0, stream>>>(wpack, gx, hbuf, (char*)gates1, ldiff, lin_w);
  k_hard<<<255, 256, 0, stream>>>(ldiff, lin_b, gumbel, hardb, nz);
  k_attn<<<256, 256, 0, stream>>>(h1f, sab, hardb, val_w, val_b, head_w, head_b, nz,
                                  out_act, out_val, out_d);
}